// Round 8
// baseline (267.071 us; speedup 1.0000x reference)
//
#include <hip/hip_runtime.h>
#include <hip/hip_bf16.h>

#define B_TOK 8192
#define D_DIM 3072
#define H_DIM 128
#define O_DIM 10
#define N_EXP 8

#define BM2 64             // k2 M-tile
#define BK2 128            // k2 K-tile (24 iters over D=3072)
#define HLDS_STRIDE 136    // bf16 elems; row byte stride 272
#define CHK 768            // k1a D-chunk
#define NCHK 4
#define ESTRIDE 4096       // static slots per expert (~48 sigma above mean 2048)

typedef __bf16 bf16x8 __attribute__((ext_vector_type(8)));
typedef float  f32x4  __attribute__((ext_vector_type(4)));
typedef unsigned short us8 __attribute__((ext_vector_type(8)));

// fp32 -> bf16 round-to-nearest-even (used where cost is amortized)
__device__ __forceinline__ unsigned short f2bf(float f) {
  unsigned int u = __float_as_uint(f);
  unsigned int r = (u + 0x7FFFu + ((u >> 16) & 1u)) >> 16;
  return (unsigned short)r;
}

// pack 2 fp32 -> 2 bf16 (round-half-up; max error 0.5 ulp, same bound as RNE)
__device__ __forceinline__ unsigned int pk2(float a, float b) {
  unsigned int ua = (__float_as_uint(a) + 0x8000u) >> 16;
  unsigned int ub = (__float_as_uint(b) + 0x8000u) & 0xFFFF0000u;
  return ub | ua;
}

__device__ __forceinline__ void async16(const void* g, void* l) {
  __builtin_amdgcn_global_load_lds(
      (const __attribute__((address_space(1))) void*)g,
      (__attribute__((address_space(3))) void*)l,
      16, 0, 0);
}

// ---------------- K0: W1 [8][3072][128] fp32 -> W1^T [8][128][3072] bf16 ----------------
__global__ __launch_bounds__(256) void k0_w1_transpose(const float* __restrict__ W1,
                                                       unsigned short* __restrict__ w1t) {
  __shared__ __align__(16) unsigned short lds[64 * 72];  // [h][72]
  const int e  = blockIdx.z;
  const int d0 = blockIdx.x * 64;
  const int h0 = blockIdx.y * 64;
  const int tid = threadIdx.x;

  const float* src = W1 + ((size_t)e * D_DIM + d0) * H_DIM + h0;
  const int hl = tid & 63;   // h lane
  const int dg = tid >> 6;   // 0..3
#pragma unroll
  for (int k = 0; k < 16; ++k) {
    const int d = dg + 4 * k;
    lds[hl * 72 + d] = f2bf(src[(size_t)d * H_DIM + hl]);
  }
  __syncthreads();

  unsigned short* dst = w1t + ((size_t)e * H_DIM + h0) * D_DIM + d0;
  const int q  = tid & 7;    // d-oct
  const int h1 = tid >> 3;   // 0..31
#pragma unroll
  for (int k = 0; k < 2; ++k) {
    const int h = h1 + 32 * k;
    const int d = q * 8;
    us8 v = *(const us8*)(lds + h * 72 + d);
    *(us8*)(dst + (size_t)h * D_DIM + d) = v;
  }
}

// ---------------- K1a: pure fp32 gating streamer (no xb) ----------------
// 8 tokens/wave, 32 tokens/block, grid (256, NCHK). Wg chunk (24 KB) in LDS.
__global__ __launch_bounds__(256) void k1a_gate(
    const float* __restrict__ x, const float* __restrict__ Wg,
    float* __restrict__ gpart) {
  __shared__ float wg_lds[N_EXP * CHK];  // 24 KB, [n][dl]
  const int c   = blockIdx.y;
  const int d0  = c * CHK;
  const int tid = threadIdx.x;

  for (int f = tid; f < CHK * N_EXP / 4; f += 256) {
    const float4 v = ((const float4*)(Wg + (size_t)d0 * N_EXP))[f];
    const int dl  = f >> 1;
    const int nh  = (f & 1) * 4;
    wg_lds[(nh + 0) * CHK + dl] = v.x;
    wg_lds[(nh + 1) * CHK + dl] = v.y;
    wg_lds[(nh + 2) * CHK + dl] = v.z;
    wg_lds[(nh + 3) * CHK + dl] = v.w;
  }
  __syncthreads();

  const int lane = tid & 63;
  const int wv   = tid >> 6;
  const int t0   = blockIdx.x * 32 + wv * 8;
  const float* xr = x + (size_t)t0 * D_DIM + d0;

  float acc[8][N_EXP];
#pragma unroll
  for (int t = 0; t < 8; ++t)
#pragma unroll
    for (int n = 0; n < N_EXP; ++n) acc[t][n] = 0.f;

#pragma unroll
  for (int s = 0; s < CHK / 256; ++s) {
    const int dl = s * 256 + lane * 4;
    float4 w4[N_EXP];
#pragma unroll
    for (int n = 0; n < N_EXP; ++n)
      w4[n] = *(const float4*)(wg_lds + n * CHK + dl);
#pragma unroll
    for (int t = 0; t < 8; ++t) {
      const float4 xv = *(const float4*)(xr + (size_t)t * D_DIM + dl);
#pragma unroll
      for (int n = 0; n < N_EXP; ++n) {
        acc[t][n] = fmaf(xv.x, w4[n].x, acc[t][n]);
        acc[t][n] = fmaf(xv.y, w4[n].y, acc[t][n]);
        acc[t][n] = fmaf(xv.z, w4[n].z, acc[t][n]);
        acc[t][n] = fmaf(xv.w, w4[n].w, acc[t][n]);
      }
    }
  }

  // two-phase reduction: 3 butterfly steps on all 64 accs -> per-lane expert
  // select -> 3 butterfly steps on 8 values -> one coalesced 256B store.
  const int g  = lane >> 3;   // expert this lane owns
  const int tt = lane & 7;    // token this lane stores
  float v[8];
#pragma unroll
  for (int t = 0; t < 8; ++t) {
#pragma unroll
    for (int n = 0; n < N_EXP; ++n) {
      acc[t][n] += __shfl_xor(acc[t][n], 32, 64);
      acc[t][n] += __shfl_xor(acc[t][n], 16, 64);
      acc[t][n] += __shfl_xor(acc[t][n], 8, 64);
    }
    float s = acc[t][0];
#pragma unroll
    for (int n = 1; n < N_EXP; ++n) s = (g == n) ? acc[t][n] : s;
    s += __shfl_xor(s, 1, 64);
    s += __shfl_xor(s, 2, 64);
    s += __shfl_xor(s, 4, 64);
    v[t] = s;                 // total[token t][expert g], in all lanes of octet
  }
  float out = v[0];
#pragma unroll
  for (int t = 1; t < 8; ++t) out = (tt == t) ? v[t] : out;
  gpart[((size_t)c * B_TOK + t0 + tt) * N_EXP + g] = out;
}

// ---------------- K1c: sum partials, top-2 + softmax, counts + tlist ----------------
__global__ __launch_bounds__(256) void k1c_topk(
    const float* __restrict__ gpart, const float* __restrict__ bg,
    int4* __restrict__ idx4, float2* __restrict__ wts, int* __restrict__ cnt,
    int* __restrict__ tlist) {
  __shared__ int lcnt[N_EXP], gbase[N_EXP];
  __shared__ float bgs[N_EXP];
  const int tid = threadIdx.x;
  if (tid < N_EXP) { lcnt[tid] = 0; bgs[tid] = bg[tid]; }
  __syncthreads();
  const int t = blockIdx.x * 256 + tid;

  float g[N_EXP];
#pragma unroll
  for (int n = 0; n < N_EXP; ++n) g[n] = bgs[n];
#pragma unroll
  for (int c = 0; c < NCHK; ++c) {
    const float* gp = gpart + ((size_t)c * B_TOK + t) * N_EXP;
    float4 a = *(const float4*)(gp);
    float4 b = *(const float4*)(gp + 4);
    g[0] += a.x; g[1] += a.y; g[2] += a.z; g[3] += a.w;
    g[4] += b.x; g[5] += b.y; g[6] += b.z; g[7] += b.w;
  }
  int i0 = 0;
#pragma unroll
  for (int n = 1; n < N_EXP; ++n) if (g[n] > g[i0]) i0 = n;
  int i1 = (i0 == 0) ? 1 : 0;
#pragma unroll
  for (int n = 0; n < N_EXP; ++n) if (n != i0 && g[n] > g[i1]) i1 = n;
  const float e1 = expf(g[i1] - g[i0]);
  const float inv = 1.f / (1.f + e1);
  const int lp0 = atomicAdd(&lcnt[i0], 1);
  const int lp1 = atomicAdd(&lcnt[i1], 1);
  __syncthreads();
  if (tid < N_EXP) gbase[tid] = atomicAdd(&cnt[tid], lcnt[tid]);
  __syncthreads();
  int p0 = gbase[i0] + lp0; p0 = p0 < ESTRIDE ? p0 : ESTRIDE - 1;
  int p1 = gbase[i1] + lp1; p1 = p1 < ESTRIDE ? p1 : ESTRIDE - 1;
  tlist[i0 * ESTRIDE + p0] = t;
  tlist[i1 * ESTRIDE + p1] = t;
  idx4[t] = make_int4(i0, p0, i1, p1);
  wts[t]  = make_float2(inv, e1 * inv);
}

// ---------------- K2: sparse experts, A from x fp32 (in-register cvt) ----------------
// BM=64, BK=128, dbuf. A: gathered fp32 rows -> VGPR -> bf16 pack -> swizzled
// ds_write_b128 (issued AFTER the MFMA phase so load latency hides under compute).
// B: w1t bf16 via swizzled global_load_lds. Rotate-by-row swizzle keeps all LDS
// traffic at the free 2-way aliasing level.
// LDS elems: buf p: A at p*24576 (8192), B at 8192+p*24576 (16384); w2t at 49152.
__global__ __launch_bounds__(256) void k2_experts(
    const float* __restrict__ x,              // [B][D] fp32
    const unsigned short* __restrict__ w1t,   // [N][H][D] bf16
    const float* __restrict__ b1,
    const float* __restrict__ W2,
    const float* __restrict__ b2,
    const int* __restrict__ cnt, const int* __restrict__ tlist,
    float* __restrict__ ypair) {              // [N*ESTRIDE][16]
  const int e    = blockIdx.y;
  int n_e        = cnt[e];
  n_e            = n_e < ESTRIDE ? n_e : ESTRIDE;
  const int row0 = blockIdx.x * BM2;
  if (row0 >= n_e) return;

  __shared__ __align__(16) unsigned short sm[51200];  // 100 KB
  unsigned short* h_lds   = sm;         // 64*136 overlay (epilogue only)
  unsigned short* w2t_lds = sm + 49152;

  const int tid  = threadIdx.x;
  const int lane = tid & 63;
  const int wv   = tid >> 6;
  const int quad = lane >> 4;
  const int cl   = lane & 15;

  // A: 4 tasks/wave; task w covers rows wv*16 + w*4 + quad, lane loads k-block cl
  const float* Abase[4];
#pragma unroll
  for (int w = 0; w < 4; ++w) {
    int gr = row0 + wv * 16 + w * 4 + quad;
    gr = gr < n_e ? gr : n_e - 1;
    Abase[w] = x + (size_t)tlist[e * ESTRIDE + gr] * D_DIM + cl * 8;
  }
  // B: 8 chunks/wave; chunk j covers rows wv*32 + j*4 + quad (global k rotated)
  const unsigned short* Bbase[8];
#pragma unroll
  for (int j = 0; j < 8; ++j) {
    const int rloc = wv * 32 + j * 4 + quad;
    const int koff = ((cl - (j * 4 + quad)) & 15) * 8;
    Bbase[j] = w1t + ((size_t)e * H_DIM + rloc) * D_DIM + koff;
  }

  float4 av[4][2];  // A-hold registers (live across MFMA phase)

#define STAGE_LOAD(it, pp)                                                \
  {                                                                       \
    const int ko = (it) * BK2;                                            \
    _Pragma("unroll")                                                     \
    for (int w = 0; w < 4; ++w) {                                         \
      av[w][0] = *(const float4*)(Abase[w] + ko);                         \
      av[w][1] = *(const float4*)(Abase[w] + ko + 4);                     \
    }                                                                     \
    unsigned short* bbuf = sm + 8192 + (pp) * 24576;                      \
    _Pragma("unroll")                                                     \
    for (int j = 0; j < 8; ++j)                                           \
      async16(Bbase[j] + ko, bbuf + (wv * 32 + j * 4) * BK2);             \
  }

#define STAGE_WRITE(pp)                                                   \
  {                                                                       \
    unsigned short* abuf = sm + (pp) * 24576;                             \
    _Pragma("unroll")                                                     \
    for (int w = 0; w < 4; ++w) {                                         \
      const int rloc = wv * 16 + w * 4 + quad;                            \
      uint4 pk;                                                           \
      pk.x = pk2(av[w][0].x, av[w][0].y);                                 \
      pk.y = pk2(av[w][0].z, av[w][0].w);                                 \
      pk.z = pk2(av[w][1].x, av[w][1].y);                                 \
      pk.w = pk2(av[w][1].z, av[w][1].w);                                 \
      *(uint4*)(abuf + rloc * BK2 + ((cl + rloc) & 15) * 8) = pk;         \
    }                                                                     \
  }

  STAGE_LOAD(0, 0);
  STAGE_WRITE(0);

  // stage W2^T swizzled: (o, hh) -> o*128 + (((hh>>3)+o)&15)*8 + (hh&7)
  const float* W2e = W2 + (size_t)e * H_DIM * O_DIM;
  for (int idx = tid; idx < 16 * 128; idx += 256) {
    const int o = idx >> 7, hh = idx & 127;
    const float v = (o < O_DIM) ? W2e[hh * O_DIM + o] : 0.f;
    w2t_lds[o * 128 + ((((hh >> 3) + o) & 15) * 8) + (hh & 7)] = f2bf(v);
  }

  const int mhalf = (wv >> 1) * 32;
  const int nhalf = (wv & 1) * 64;

  f32x4 acc[2][4];
#pragma unroll
  for (int i = 0; i < 2; ++i)
#pragma unroll
    for (int j = 0; j < 4; ++j)
      acc[i][j] = (f32x4){0.f, 0.f, 0.f, 0.f};

  const int NIT = D_DIM / BK2;  // 24
  for (int it = 0; it < NIT; ++it) {
    __syncthreads();                       // buf[it&1] ready
    const int pp = it & 1, np = pp ^ 1;
    if (it + 1 < NIT) STAGE_LOAD(it + 1, np);
    const unsigned short* al = sm + pp * 24576;
    const unsigned short* bl = sm + 8192 + pp * 24576;
#pragma unroll
    for (int kk = 0; kk < 4; ++kk) {
      const int pos = ((kk * 4 + quad + cl) & 15) * 8;
      bf16x8 af[2], bfr[4];
#pragma unroll
      for (int mi = 0; mi < 2; ++mi)
        af[mi] = *(const bf16x8*)(al + (mhalf + mi * 16 + cl) * BK2 + pos);
#pragma unroll
      for (int ni = 0; ni < 4; ++ni)
        bfr[ni] = *(const bf16x8*)(bl + (nhalf + ni * 16 + cl) * BK2 + pos);
#pragma unroll
      for (int mi = 0; mi < 2; ++mi)
#pragma unroll
        for (int ni = 0; ni < 4; ++ni)
          acc[mi][ni] = __builtin_amdgcn_mfma_f32_16x16x32_bf16(af[mi], bfr[ni], acc[mi][ni], 0, 0, 0);
    }
    if (it + 1 < NIT) STAGE_WRITE(np);
  }
  __syncthreads();   // all waves done with LDS bufs before h overlays buf0

  // epilogue 1: h = relu(acc + b1) -> h_lds. C/D layout: col=lane&15, row=quad*4+r
  const float* b1e = b1 + e * H_DIM;
#pragma unroll
  for (int ni = 0; ni < 4; ++ni) {
    const int col  = nhalf + ni * 16 + cl;
    const float bias = b1e[col];
#pragma unroll
    for (int mi = 0; mi < 2; ++mi) {
      const int rbase = mhalf + mi * 16 + (quad << 2);
#pragma unroll
      for (int r = 0; r < 4; ++r) {
        float v = acc[mi][ni][r] + bias;
        v = v > 0.f ? v : 0.f;
        h_lds[(rbase + r) * HLDS_STRIDE + col] = f2bf(v);
      }
    }
  }
  __syncthreads();

  // epilogue 2: y[64x16] = h[64x128] @ W2[128x16]; wave handles 16 rows
  f32x4 acc2 = (f32x4){0.f, 0.f, 0.f, 0.f};
#pragma unroll
  for (int ks = 0; ks < 4; ++ks) {
    const int krd = ks * 32 + quad * 8;
    bf16x8 bfr = *(const bf16x8*)(w2t_lds + cl * 128 + ((ks * 4 + quad + cl) & 15) * 8);
    bf16x8 afr = *(const bf16x8*)(h_lds + (wv * 16 + cl) * HLDS_STRIDE + krd);
    acc2 = __builtin_amdgcn_mfma_f32_16x16x32_bf16(afr, bfr, acc2, 0, 0, 0);
  }
  const int o = cl;
  if (o < O_DIM) {
    const float bias2 = b2[e * O_DIM + o];
#pragma unroll
    for (int r = 0; r < 4; ++r) {
      const int rl = wv * 16 + (quad << 2) + r;
      if (row0 + rl < n_e)
        ypair[(size_t)(e * ESTRIDE + row0 + rl) * 16 + o] = acc2[r] + bias2;
    }
  }
}

// ---------------- K3: combine top-2 via static slots ----------------
__global__ __launch_bounds__(256) void k3_combine(
    const float* __restrict__ ypair, const int4* __restrict__ idx4,
    const float2* __restrict__ wts, float* __restrict__ out) {
  const int g = blockIdx.x * 256 + threadIdx.x;
  if (g >= B_TOK * O_DIM) return;
  const int b = g / O_DIM, o = g - b * O_DIM;
  const int4 r = idx4[b];
  const float2 w = wts[b];
  out[g] = w.x * ypair[(size_t)(r.x * ESTRIDE + r.y) * 16 + o] +
           w.y * ypair[(size_t)(r.z * ESTRIDE + r.w) * 16 + o];
}

extern "C" void kernel_launch(void* const* d_in, const int* in_sizes, int n_in,
                              void* d_out, int out_size, void* d_ws, size_t ws_size,
                              hipStream_t stream) {
  const float* x  = (const float*)d_in[0];
  const float* Wg = (const float*)d_in[1];
  const float* bg = (const float*)d_in[2];
  const float* W1 = (const float*)d_in[3];
  const float* b1 = (const float*)d_in[4];
  const float* W2 = (const float*)d_in[5];
  const float* b2 = (const float*)d_in[6];
  float* out = (float*)d_out;

  char* ws = (char*)d_ws;
  unsigned short* w1t = (unsigned short*)ws;                 // 6291456 B
  int4*   idx4  = (int4*)  (ws + 6291456);                   // 131072 B
  float2* wts   = (float2*)(ws + 6422528);                   // 65536 B
  int*    cnt   = (int*)   (ws + 6488064);                   // 128 B
  int*    tlist = (int*)   (ws + 6488192);                   // 131072 B
  // gpart (1 MB) overlays ypair (2 MB): gpart dead after k1c; ypair written by k2.
  float*  gpart = (float*) (ws + 6619264);
  float*  ypair = (float*) (ws + 6619264);                   // total ws ~8.7 MB

  k0_w1_transpose<<<dim3(48, 2, 8), dim3(256), 0, stream>>>(W1, w1t);
  (void)hipMemsetAsync(cnt, 0, N_EXP * sizeof(int), stream);
  k1a_gate<<<dim3(B_TOK / 32, NCHK), dim3(256), 0, stream>>>(x, Wg, gpart);
  k1c_topk<<<dim3(B_TOK / 256), dim3(256), 0, stream>>>(gpart, bg, idx4, wts, cnt, tlist);
  k2_experts<<<dim3(ESTRIDE / BM2, N_EXP), dim3(256), 0, stream>>>(
      x, w1t, b1, W2, b2, cnt, tlist, ypair);
  k3_combine<<<dim3((B_TOK * O_DIM + 255) / 256), dim3(256), 0, stream>>>(
      ypair, idx4, wts, out);
}